// Round 1
// 52.440 us; speedup vs baseline: 1.9104x; 1.9104x over previous
//
#include <hip/hip_runtime.h>

#define DD 6
#define FF 64
#define LN_EPS 1e-5f

// DPP cross-lane move within a 16-lane row (VALU pipe, not DS).
// 0x140=row_mirror (partner l^15), 0x141=row_half_mirror (l^7),
// 0x4E=quad_perm[2,3,0,1] (l^2), 0xB1=quad_perm[1,0,3,2] (l^1).
template <int CTRL>
__device__ inline float dpp_mov(float x) {
    return __int_as_float(__builtin_amdgcn_update_dpp(
        0, __float_as_int(x), CTRL, 0xF, 0xF, true));
}

// Pass 1: fused stalk-mean + per-entity LN/matvec partials.
// tab[ent*8] = {S, SS, d0..d5} with S=sum_k m_k, SS=sum_k m_k^2,
// d_j = sum_k m_k*gamma[base+k]*W[base+k][j] (base 0 nodes / 64 edges).
// 16-lane group handles entity pair (A=2p, B=2p+1); lane gl owns feats
// 4gl..4gl+3. DPP butterfly leaves lane gl holding value index gl
// (0..7 = A, 8..15 = B) -> contiguous 64B store per group.
// Block 0 threads 0..11 also compute gw_j / bw_j scalars.
__global__ __launch_bounds__(256) void entity_kernel(
    const float* __restrict__ x, const float* __restrict__ e,
    const float* __restrict__ gamma, const float* __restrict__ beta,
    const float* __restrict__ W, const float* __restrict__ b,
    float* __restrict__ nodeT, float* __restrict__ edgeT,
    float* __restrict__ gwbw, int N, int E) {
    if (blockIdx.x == 0 && threadIdx.x < 12) {
        const int t = threadIdx.x;
        const int j = (t < 6) ? t : t - 6;
        const float* g = (t < 6) ? gamma : beta;
        float s = (t < 6) ? 0.f : b[j];
        for (int k = 0; k < 2 * FF; ++k) s = fmaf(g[k], W[k * DD + j], s);
        gwbw[t] = s;
    }

    const int gl = threadIdx.x & 15;
    const int nodePairs = (N + 1) >> 1;
    const int edgePairs = (E + 1) >> 1;
    const int p = blockIdx.x * 16 + (threadIdx.x >> 4);
    if (p >= nodePairs + edgePairs) return;

    const float* in; float* tab; int A, last, kbase;
    if (p < nodePairs) {
        in = x; tab = nodeT; A = 2 * p; last = N - 1; kbase = 0;
    } else {
        in = e; tab = edgeT; A = 2 * (p - nodePairs); last = E - 1; kbase = FF;
    }
    const int B = A + 1;
    const bool bval = (B <= last);
    const int Bc = bval ? B : A;

    // Issue the 12 float4 data loads first to overlap the gamma*W hoist.
    const float4* pa = reinterpret_cast<const float4*>(in + (size_t)A * (DD * FF)) + gl;
    const float4* pb = reinterpret_cast<const float4*>(in + (size_t)Bc * (DD * FF)) + gl;
    float4 va[DD], vb[DD];
#pragma unroll
    for (int d = 0; d < DD; ++d) { va[d] = pa[d * 16]; vb[d] = pb[d * 16]; }

    float gwl[4][6];
#pragma unroll
    for (int c = 0; c < 4; ++c) {
        const int k = kbase + 4 * gl + c;
        const float g = gamma[k];
#pragma unroll
        for (int j = 0; j < 6; ++j) gwl[c][j] = g * W[k * DD + j];
    }

    float mA[4], mB[4];
    {
        float s0 = 0.f, s1 = 0.f, s2 = 0.f, s3 = 0.f;
        float u0 = 0.f, u1 = 0.f, u2 = 0.f, u3 = 0.f;
#pragma unroll
        for (int d = 0; d < DD; ++d) {
            s0 += va[d].x; s1 += va[d].y; s2 += va[d].z; s3 += va[d].w;
            u0 += vb[d].x; u1 += vb[d].y; u2 += vb[d].z; u3 += vb[d].w;
        }
        const float inv6 = 1.0f / 6.0f;
        mA[0] = s0 * inv6; mA[1] = s1 * inv6; mA[2] = s2 * inv6; mA[3] = s3 * inv6;
        mB[0] = u0 * inv6; mB[1] = u1 * inv6; mB[2] = u2 * inv6; mB[3] = u3 * inv6;
    }

    // v[0]=SA v[1]=SSA v[2..7]=dA[0..5] v[8]=SB v[9]=SSB v[10..15]=dB[0..5]
    float v[16];
#pragma unroll
    for (int k = 0; k < 16; ++k) v[k] = 0.f;
#pragma unroll
    for (int c = 0; c < 4; ++c) {
        v[0] += mA[c];
        v[1] = fmaf(mA[c], mA[c], v[1]);
        v[8] += mB[c];
        v[9] = fmaf(mB[c], mB[c], v[9]);
#pragma unroll
        for (int j = 0; j < 6; ++j) {
            v[2 + j]  = fmaf(mA[c], gwl[c][j], v[2 + j]);
            v[10 + j] = fmaf(mB[c], gwl[c][j], v[10 + j]);
        }
    }

    float t[16];
    // stage 1: partner l^15 (row_mirror), predicate bit3; live 16 -> 8
#pragma unroll
    for (int k = 0; k < 16; ++k) t[k] = dpp_mov<0x140>(v[k]);
    if (gl & 8) {
#pragma unroll
        for (int k = 0; k < 8; ++k) { v[k] = v[8 + k]; t[k] = t[8 + k]; }
    }
#pragma unroll
    for (int k = 0; k < 8; ++k) v[k] += t[k];
    // stage 2: partner l^7 (row_half_mirror), predicate bit2; live 8 -> 4
#pragma unroll
    for (int k = 0; k < 8; ++k) t[k] = dpp_mov<0x141>(v[k]);
    if (gl & 4) {
#pragma unroll
        for (int k = 0; k < 4; ++k) { v[k] = v[4 + k]; t[k] = t[4 + k]; }
    }
#pragma unroll
    for (int k = 0; k < 4; ++k) v[k] += t[k];
    // stage 3: partner l^2 (quad_perm[2,3,0,1]), predicate bit1; live 4 -> 2
#pragma unroll
    for (int k = 0; k < 4; ++k) t[k] = dpp_mov<0x4E>(v[k]);
    if (gl & 2) { v[0] = v[2]; t[0] = t[2]; v[1] = v[3]; t[1] = t[3]; }
    v[0] += t[0]; v[1] += t[1];
    // stage 4: partner l^1 (quad_perm[1,0,3,2]), predicate bit0; live 2 -> 1
    t[0] = dpp_mov<0xB1>(v[0]);
    t[1] = dpp_mov<0xB1>(v[1]);
    if (gl & 1) { v[0] = v[1]; t[0] = t[1]; }
    const float r = v[0] + t[0];   // lane gl holds total of value index gl

    if (gl < 8) {
        tab[(size_t)A * 8 + gl] = r;
    } else if (bval) {
        tab[(size_t)B * 8 + (gl & 7)] = r;
    }
}

// Pass 2: one thread per incidence. Gather 8 floats/side (node table 3.2 MB +
// edge table 0.64 MB fit per-XCD L2), combine, sigmoid, wave-local LDS
// transpose for fully coalesced output writes.
__global__ __launch_bounds__(256) void incidence_kernel(
    const float* __restrict__ nodeT, const float* __restrict__ edgeT,
    const int* __restrict__ row, const int* __restrict__ col,
    const float* __restrict__ gwbw, float* __restrict__ out, int nnz) {
    __shared__ float lds[4][64 * DD];
    const int wid = threadIdx.x >> 6;
    const int l = threadIdx.x & 63;
    const int i = blockIdx.x * blockDim.x + threadIdx.x;
    const int ic = min(i, nnz - 1);
    const int rr = row[ic];
    const int cc = col[ic];
    const float4* np = reinterpret_cast<const float4*>(nodeT + (size_t)rr * 8);
    const float4* ep = reinterpret_cast<const float4*>(edgeT + (size_t)cc * 8);
    const float4 a0 = np[0], a1 = np[1];
    const float4 b0 = ep[0], b1 = ep[1];

    const float S  = a0.x + b0.x;
    const float SS = a0.y + b0.y;
    const float d[6] = {a0.z + b0.z, a0.w + b0.w, a1.x + b1.x,
                        a1.y + b1.y, a1.z + b1.z, a1.w + b1.w};

    const float mu  = S * (1.0f / 128.0f);
    const float var = fmaf(SS, 1.0f / 128.0f, -mu * mu);
    const float inv = rsqrtf(var + LN_EPS);

#pragma unroll
    for (int j = 0; j < 6; ++j) {
        const float pre = fmaf(inv, fmaf(-mu, gwbw[j], d[j]), gwbw[6 + j]);
        lds[wid][l * DD + j] = 1.0f / (1.0f + __expf(-pre));
    }
    __syncthreads();
    const size_t base = (size_t)(blockIdx.x * blockDim.x + wid * 64) * DD;
    const size_t lim = (size_t)nnz * DD;
#pragma unroll
    for (int j = 0; j < 6; ++j) {
        const int f = j * 64 + l;
        if (base + (size_t)f < lim)
            __builtin_nontemporal_store(lds[wid][f], &out[base + (size_t)f]);
    }
}

extern "C" void kernel_launch(void* const* d_in, const int* in_sizes, int n_in,
                              void* d_out, int out_size, void* d_ws, size_t ws_size,
                              hipStream_t stream) {
    const float* x     = (const float*)d_in[0];
    const float* e     = (const float*)d_in[1];
    const int*   row   = (const int*)d_in[2];
    const int*   col   = (const int*)d_in[3];
    const float* gamma = (const float*)d_in[4];
    const float* beta  = (const float*)d_in[5];
    const float* W     = (const float*)d_in[6];
    const float* b     = (const float*)d_in[7];
    float* out = (float*)d_out;

    const int N   = in_sizes[0] / (DD * FF);   // 100000 (element-count convention)
    const int E   = in_sizes[1] / (DD * FF);   // 20000
    const int NNZ = in_sizes[2];               // 1000000

    float* nodeT = (float*)d_ws;               // N*8 f32 = 3.2 MB
    float* edgeT = nodeT + (size_t)N * 8;      // E*8 f32 = 0.64 MB
    float* gwbw  = edgeT + (size_t)E * 8;      // 12 f32

    {
        const int totalPairs = ((N + 1) >> 1) + ((E + 1) >> 1);
        const int blocks = (totalPairs + 15) / 16;     // 3750
        entity_kernel<<<blocks, 256, 0, stream>>>(x, e, gamma, beta, W, b,
                                                  nodeT, edgeT, gwbw, N, E);
    }
    {
        const int blocks = (NNZ + 255) / 256;          // 3907
        incidence_kernel<<<blocks, 256, 0, stream>>>(nodeT, edgeT, row, col,
                                                     gwbw, out, NNZ);
    }
}